// Round 9
// baseline (437.405 us; speedup 1.0000x reference)
//
#include <hip/hip_runtime.h>
#include <stdint.h>
#include <math.h>

#define NOISE_LEVEL 0.02f
#define CROSSTALK   0.05f
#define COHERENCE   0.03f

typedef _Float16 half8 __attribute__((ext_vector_type(8)));
typedef _Float16 half4 __attribute__((ext_vector_type(4)));
typedef __attribute__((ext_vector_type(4))) float f32x4;

#define TF_ROUND(x0,x1,R) { x0 += x1; x1 = ((x1 << (R)) | (x1 >> (32-(R)))); x1 ^= x0; }

__host__ __device__ inline void threefry2x32(uint32_t k0, uint32_t k1,
                                             uint32_t x0, uint32_t x1,
                                             uint32_t& o0, uint32_t& o1)
{
  uint32_t ks2 = k0 ^ k1 ^ 0x1BD11BDAu;
  x0 += k0; x1 += k1;
  TF_ROUND(x0,x1,13) TF_ROUND(x0,x1,15) TF_ROUND(x0,x1,26) TF_ROUND(x0,x1,6)
  x0 += k1; x1 += ks2 + 1u;
  TF_ROUND(x0,x1,17) TF_ROUND(x0,x1,29) TF_ROUND(x0,x1,16) TF_ROUND(x0,x1,24)
  x0 += ks2; x1 += k0 + 2u;
  TF_ROUND(x0,x1,13) TF_ROUND(x0,x1,15) TF_ROUND(x0,x1,26) TF_ROUND(x0,x1,6)
  x0 += k0; x1 += k1 + 3u;
  TF_ROUND(x0,x1,17) TF_ROUND(x0,x1,29) TF_ROUND(x0,x1,16) TF_ROUND(x0,x1,24)
  x0 += k1; x1 += ks2 + 4u;
  TF_ROUND(x0,x1,13) TF_ROUND(x0,x1,15) TF_ROUND(x0,x1,26) TF_ROUND(x0,x1,6)
  o0 = x0 + ks2; o1 = x1 + k0 + 5u;
}

// threefry_partitionable bits for 32-bit draws: XOR of the two output words.
__device__ inline uint32_t jax_bits(uint32_t k0, uint32_t k1, uint32_t idx)
{
  uint32_t o0, o1; threefry2x32(k0, k1, 0u, idx, o0, o1); return o0 ^ o1;
}

// JAX random.normal(float32): u ~ uniform[-0.99999994, 1); n = sqrt(2)*erfinv(u)
// Rare erfinv branch evaluated only when some lane needs it (identical per-lane
// results; ~80% of waves skip it).
__device__ inline float jax_normal(uint32_t k0, uint32_t k1, uint32_t idx)
{
  uint32_t bits = jax_bits(k0, k1, idx);
  float f = __uint_as_float((bits >> 9) | 0x3f800000u) - 1.0f;   // [0,1)
  float u = fmaf(f, 2.0f, -0.99999994f);
  u = fmaxf(-0.99999994f, u);
  float w = -__logf(fmaf(-u, u, 1.0f));
  float wl = w - 2.5f;
  float p = 2.81022636e-08f;
  p = fmaf(p, wl, 3.43273939e-07f);
  p = fmaf(p, wl, -3.5233877e-06f);
  p = fmaf(p, wl, -4.39150654e-06f);
  p = fmaf(p, wl, 0.00021858087f);
  p = fmaf(p, wl, -0.00125372503f);
  p = fmaf(p, wl, -0.00417768164f);
  p = fmaf(p, wl, 0.246640727f);
  p = fmaf(p, wl, 1.50140941f);
  if (__any(w >= 5.0f)) {
    float ws = sqrtf(w) - 3.0f;
    float q = -0.000200214257f;
    q = fmaf(q, ws, 0.000100950558f);
    q = fmaf(q, ws, 0.00134934322f);
    q = fmaf(q, ws, -0.00367342844f);
    q = fmaf(q, ws, 0.00573950773f);
    q = fmaf(q, ws, -0.0076224613f);
    q = fmaf(q, ws, 0.00943887047f);
    q = fmaf(q, ws, 1.00167406f);
    q = fmaf(q, ws, 2.83297682f);
    p = (w >= 5.0f) ? q : p;
  }
  return 1.41421354f * (p * u);
}

__device__ inline float cos_small(float p)
{
  float p2 = p * p;
  return 1.0f + p2 * (-0.5f + p2 * (4.16666679e-02f + p2 * (-1.38888892e-03f)));
}

// exact-algebra tanh via fast exp; abs err <= ~1.2e-7, inf-safe.
__device__ inline float tanh_fast(float x)
{
  float ax = fabsf(x);
  float e = __expf(2.0f * ax);
  float r = 1.0f - 2.0f / (e + 1.0f);
  return copysignf(r, x);
}

// ---------------------------------------------------------------------------
// Packed fp16 operand layout (BKT=32): tile (rb,kt) at
//   halves [(rb*ktiles + kt)*4096, +4096), internally [kq(4)][row(128)][8].
// Fragment-native fp16 OUTPUT layout (C of a 128x128 block):
//   idx = (tile16*4 + w)*4096 + (fn*16+fm*4+j)*64 + lane
// ---------------------------------------------------------------------------

// pack_plane: fp32 [R][K] -> packed fp16 operand plane (optional tanh first).
__global__ __launch_bounds__(256)
void pack_plane(const float* __restrict__ in, _Float16* __restrict__ out,
                int R, int K, int kshift, int do_tanh)
{
  const int nslots = R * (K >> 3);
  const int ktm = (K >> 5) - 1;
  int g = blockIdx.x * 256 + threadIdx.x;
  const int stride = gridDim.x * 256;
  for (; g < nslots; g += stride) {
    int tile = g >> 9;
    int s = g & 511;
    int kq = s >> 7, row = s & 127;
    int rb = tile >> kshift, kt = tile & ktm;
    int r = rb * 128 + row;
    int k = kt * 32 + kq * 8;
    const float* src = in + (size_t)r * K + k;
    float4 v0 = *(const float4*)src;
    float4 v1 = *(const float4*)(src + 4);
    float xs[8] = {v0.x, v0.y, v0.z, v0.w, v1.x, v1.y, v1.z, v1.w};
    half8 h;
    #pragma unroll
    for (int e = 0; e < 8; ++e) {
      float x = do_tanh ? tanh_fast(xs[e]) : xs[e];
      h[e] = (_Float16)x;
    }
    *(half8*)&out[(size_t)g * 8] = h;
  }
}

// decode fragment-native index for (r, c) with 16 col-blocks (N=2048)
__device__ __forceinline__ size_t cnat_idx(int r, int c)
{
  int bm = r >> 7, bn = c >> 7, rr = r & 127, cc = c & 127;
  int w = ((rr >> 6) << 1) | (cc >> 6);
  int fm = (rr >> 4) & 3, lg = (rr >> 2) & 3, j = rr & 3;
  int fn = (cc >> 4) & 3, lm = cc & 15;
  return (((size_t)(bm * 16 + bn) * 4 + w) * 4096)
         + (size_t)(fn * 16 + fm * 4 + j) * 64 + lg * 16 + lm;
}

// coherence + thermal-decompose + pack: reads G1 out (fragment-native fp16),
// full = (x + tn) with phase interference; small = full - tn[col] -> packed fp16.
__global__ __launch_bounds__(256)
void coherence_pack_small(const _Float16* __restrict__ xn, const float* __restrict__ tn,
                          _Float16* __restrict__ out,
                          uint32_t pk0, uint32_t pk1, int R, int K, int kshift)
{
  const int nslots = R * (K >> 3);
  const int ktm = (K >> 5) - 1;
  int g = blockIdx.x * 256 + threadIdx.x;
  const int stride = gridDim.x * 256;
  for (; g < nslots; g += stride) {
    int tile = g >> 9;
    int s = g & 511;
    int kq = s >> 7, row = s & 127;
    int rb = tile >> kshift, kt = tile & ktm;
    int r = rb * 128 + row;
    int k = kt * 32 + kq * 8;
    half8 xv = *(const half8*)&xn[cnat_idx(r, k)];   // 8 consecutive cols
    float4 t0 = *(const float4*)&tn[k];
    float4 t1 = *(const float4*)&tn[k + 4];
    float ts[8] = {t0.x, t0.y, t0.z, t0.w, t1.x, t1.y, t1.z, t1.w};
    uint32_t fb = (uint32_t)(r * K + k);
    half8 h;
    #pragma unroll
    for (int e = 0; e < 8; ++e) {
      float vv = (float)xv[e] + ts[e];
      float ph = COHERENCE * jax_normal(pk0, pk1, fb + e);
      float cp = cos_small(ph);
      float xvv = vv + (vv * cp - vv) * COHERENCE;
      h[e] = (_Float16)(xvv - ts[e]);
    }
    *(half8*)&out[(size_t)g * 8] = h;
  }
}

// bias_fold: fold[j] = b[j] + sum_h tn[h] * W[j,h]   (fp32, one wave per j)
__global__ __launch_bounds__(256)
void bias_fold(const float* __restrict__ tn, const float* __restrict__ W,
               const float* __restrict__ b, float* __restrict__ fold, int K)
{
  const int wid = threadIdx.x >> 6;
  const int lane = threadIdx.x & 63;
  const int j = blockIdx.x * 4 + wid;
  const float* row = W + (size_t)j * K;
  float s = 0.0f;
  for (int h = lane; h < K; h += 64) s = fmaf(tn[h], row[h], s);
  #pragma unroll
  for (int off = 32; off > 0; off >>= 1) s += __shfl_down(s, off);
  if (lane == 0) fold[j] = b[j] + s;
}

// ---------------------------------------------------------------------------
// Single-plane fp16 MFMA GEMM, BKT=32, LDS 32 KiB -> 5 blocks/CU (the round-8
// bottleneck was 2 blocks/CU: threefry dep-chains latency-exposed at 1.6
// waves/SIMD). In-loop RNG (16 f32x4 groups over first 16 k-steps, named regs)
// and fragment-native fp16 out retained. MFMA k-order identical to round 8.
// ---------------------------------------------------------------------------
#define BM 128
#define BN 128
#define TILEH 4096            // halves per operand tile (128*32)
#define BUFH  (2 * TILEH)

__device__ __forceinline__ f32x4 noise_group(int g, int blockM, int blockN,
                                             int wr, int wc, int lg, int lm,
                                             int N, uint32_t k0, uint32_t k1)
{
  int fn = g >> 2, fm = g & 3;
  int gr0 = blockM + wr * 64 + fm * 16 + lg * 4;
  int gc  = blockN + wc * 64 + fn * 16 + lm;
  f32x4 r;
  #pragma unroll
  for (int j = 0; j < 4; ++j)
    r[j] = jax_normal(k0, k1, (uint32_t)((gr0 + j) * N + gc));
  return r;
}

__global__ __launch_bounds__(256)
void gemm_f16(const _Float16* __restrict__ Ap, const _Float16* __restrict__ Bp,
              const float* __restrict__ bias, _Float16* __restrict__ outn,
              float* __restrict__ colabs, int M, int N, int K,
              uint32_t nk0, uint32_t nk1)
{
  __shared__ __align__(16) _Float16 lds[2 * BUFH];   // 32 KiB

  const int t = threadIdx.x;
  const int nwg = gridDim.x;
  const int wg = (blockIdx.x & 7) * (nwg >> 3) + (blockIdx.x >> 3);
  const int nbn = N / BN;
  const int bn = wg & (nbn - 1);       // bn-minor: consecutive wgs share A panel
  const int bm = wg / nbn;
  const int blockM = bm * BM, blockN = bn * BN;

  const int lane = t & 63;
  const int w = t >> 6;
  const int wr = w >> 1, wc = w & 1;
  const int lm = lane & 15, lg = lane >> 4;

  // staging: wave w copies half an operand tile (4 KiB = 4 x 1KiB insts)
  const int op = w >> 1;               // 0 = A, 1 = B
  const int part = w & 1;
  const _Float16* gplane = op ? Bp : Ap;
  const int blk = op ? bn : bm;
  const int ktiles = K >> 5;
  const _Float16* gsrc0 = gplane + ((size_t)blk * ktiles) * TILEH
                          + part * (TILEH / 2) + lane * 8;
  _Float16* lbase = lds + op * TILEH + part * (TILEH / 2);

#define STAGE(buf, kt_) {                                                      \
    _Float16* lp = lbase + (buf) * BUFH;                                       \
    const _Float16* s = gsrc0 + (size_t)(kt_) * TILEH;                         \
    _Pragma("unroll")                                                          \
    for (int i = 0; i < 4; ++i)                                                \
      __builtin_amdgcn_global_load_lds((const void*)(s + i * 512),             \
                                       (void*)(lp + i * 512), 16, 0, 0);       \
  }

  f32x4 acc[4][4];
  #pragma unroll
  for (int i = 0; i < 4; ++i)
    #pragma unroll
    for (int j = 0; j < 4; ++j) acc[i][j] = 0.0f;

  f32x4 nz0 = 0.0f, nz1 = 0.0f, nz2 = 0.0f, nz3 = 0.0f;
  f32x4 nz4 = 0.0f, nz5 = 0.0f, nz6 = 0.0f, nz7 = 0.0f;
  f32x4 nz8 = 0.0f, nz9 = 0.0f, nz10 = 0.0f, nz11 = 0.0f;
  f32x4 nz12 = 0.0f, nz13 = 0.0f, nz14 = 0.0f, nz15 = 0.0f;

  const int nk = ktiles;               // 32 (G1) or 64 (G2)
  STAGE(0, 0);
  __syncthreads();
  int cur = 0;

  for (int kt = 0; kt < nk; ++kt) {
    if (kt + 1 < nk) STAGE(cur ^ 1, kt + 1);

    const _Float16* base = lds + cur * BUFH;
    half8 fa[4], fb[4];
    #pragma unroll
    for (int fm = 0; fm < 4; ++fm)
      fa[fm] = *(const half8*)(base + lg * 1024 + (wr * 64 + fm * 16 + lm) * 8);
    #pragma unroll
    for (int fn = 0; fn < 4; ++fn)
      fb[fn] = *(const half8*)(base + TILEH + lg * 1024 + (wc * 64 + fn * 16 + lm) * 8);
    #pragma unroll
    for (int fm = 0; fm < 4; ++fm)
      #pragma unroll
      for (int fn = 0; fn < 4; ++fn)
        acc[fm][fn] = __builtin_amdgcn_mfma_f32_16x16x32_f16(fa[fm], fb[fn], acc[fm][fn], 0, 0, 0);

    // in-loop RNG: one 4-normal group per step (first 16 steps); VALU overlaps
    // the MFMA pipe + staging latency. kt is wave-uniform.
    if (kt < 16) {
      f32x4 v = noise_group(kt, blockM, blockN, wr, wc, lg, lm, N, nk0, nk1);
      switch (kt) {
        case 0:  nz0  = v; break;  case 1:  nz1  = v; break;
        case 2:  nz2  = v; break;  case 3:  nz3  = v; break;
        case 4:  nz4  = v; break;  case 5:  nz5  = v; break;
        case 6:  nz6  = v; break;  case 7:  nz7  = v; break;
        case 8:  nz8  = v; break;  case 9:  nz9  = v; break;
        case 10: nz10 = v; break;  case 11: nz11 = v; break;
        case 12: nz12 = v; break;  case 13: nz13 = v; break;
        case 14: nz14 = v; break;  default: nz15 = v; break;
      }
    }

    __syncthreads();
    cur ^= 1;
  }

  // epilogue: fragment-native stores (64 lanes x 2B = one 128B line each)
  const size_t obase = (((size_t)(bm * nbn + bn) * 4 + w) * 4096) + lane;

#define EPI_STORE(fm_, fn_, NZV)                                               \
    _Pragma("unroll")                                                          \
    for (int j = 0; j < 4; ++j) {                                              \
      float v = tanh_fast(acc[fm_][fn_][j] + bv) + NOISE_LEVEL * NZV[j];       \
      outn[obase + (size_t)((fn_)*16 + (fm_)*4 + j) * 64] = (_Float16)v;       \
      cp += fabsf(v);                                                          \
    }

#define EPI_FN(fn_, NZA, NZB, NZC, NZD) {                                      \
    const int gc = blockN + wc * 64 + (fn_)*16 + lm;                           \
    const float bv = bias[gc];                                                 \
    float cp = 0.0f;                                                           \
    EPI_STORE(0, fn_, NZA) EPI_STORE(1, fn_, NZB)                              \
    EPI_STORE(2, fn_, NZC) EPI_STORE(3, fn_, NZD)                              \
    cp += __shfl_xor(cp, 16);                                                  \
    cp += __shfl_xor(cp, 32);                                                  \
    if (lg == 0) atomicAdd(&colabs[gc], cp);                                   \
  }

  EPI_FN(0, nz0,  nz1,  nz2,  nz3)
  EPI_FN(1, nz4,  nz5,  nz6,  nz7)
  EPI_FN(2, nz8,  nz9,  nz10, nz11)
  EPI_FN(3, nz12, nz13, nz14, nz15)
#undef EPI_FN
#undef EPI_STORE
#undef STAGE
}

// ---------------------------------------------------------------------------
// thermal = 0.7*prev + 0.3*(colabs*CROSSTALK); tn[i] = CROSSTALK * sum thermal[j]/(i-j)^2
// ---------------------------------------------------------------------------
__global__ __launch_bounds__(256)
void thermal_tn(const float* __restrict__ colabs, const float* __restrict__ prev_thermal,
                float* __restrict__ thermal_out, float* __restrict__ tn_out, int has_prev)
{
  __shared__ float th[2048];
  __shared__ float inv[2048];
  const int t = threadIdx.x;
  for (int j = t; j < 2048; j += 256) {
    float lt = colabs[j] * CROSSTALK;
    float pv = has_prev ? prev_thermal[j] : 0.0f;
    th[j] = 0.7f * pv + 0.3f * lt;
    float d = (float)j;
    inv[j] = (j == 0) ? 0.0f : 1.0f / (d * d);
  }
  __syncthreads();
  const int i = blockIdx.x * 256 + t;
  float s = 0.0f;
  #pragma unroll 4
  for (int j = 0; j < 2048; ++j) {
    int d = i - j; d = d < 0 ? -d : d;
    s += th[j] * inv[d];
  }
  tn_out[i] = s * CROSSTALK;
  thermal_out[i] = th[i];
}

// ---------------------------------------------------------------------------
// Final: x2 = (a2 + tn2) with coherence; out[b,:] = x2[b,:] @ Wout^T + bout.
// a2 is fragment-native fp16.
// ---------------------------------------------------------------------------
__global__ __launch_bounds__(256)
void final_out(const _Float16* __restrict__ a2n, const float* __restrict__ tn2,
               const float* __restrict__ Wout, const float* __restrict__ bout,
               float* __restrict__ out, uint32_t pk0, uint32_t pk1)
{
  const int wave = threadIdx.x >> 6;
  const int lane = threadIdx.x & 63;
  const int b = blockIdx.x * 4 + wave;
  float acc0 = 0.0f, acc1 = 0.0f;
  #pragma unroll
  for (int i = 0; i < 8; ++i) {
    int h = lane * 4 + i * 256;
    half4 v4 = *(const half4*)&a2n[cnat_idx(b, h)];
    float4 tv = *(const float4*)&tn2[h];
    float4 w0 = *(const float4*)&Wout[h];
    float4 w1 = *(const float4*)&Wout[2048 + h];
    float xs[4]  = {(float)v4[0] + tv.x, (float)v4[1] + tv.y,
                    (float)v4[2] + tv.z, (float)v4[3] + tv.w};
    float w0s[4] = {w0.x, w0.y, w0.z, w0.w};
    float w1s[4] = {w1.x, w1.y, w1.z, w1.w};
    uint32_t fb = (uint32_t)(b * 2048 + h);
    #pragma unroll
    for (int e = 0; e < 4; ++e) {
      float ph = COHERENCE * jax_normal(pk0, pk1, fb + e);
      float cp = cos_small(ph);
      float xv = xs[e] + (xs[e] * cp - xs[e]) * COHERENCE;
      acc0 = fmaf(xv, w0s[e], acc0);
      acc1 = fmaf(xv, w1s[e], acc1);
    }
  }
  #pragma unroll
  for (int off = 32; off > 0; off >>= 1) {
    acc0 += __shfl_down(acc0, off);
    acc1 += __shfl_down(acc1, off);
  }
  if (lane == 0) {
    out[(size_t)b * 2 + 0] = acc0 + bout[0];
    out[(size_t)b * 2 + 1] = acc1 + bout[1];
  }
}

extern "C" void kernel_launch(void* const* d_in, const int* in_sizes, int n_in,
                              void* d_out, int out_size, void* d_ws, size_t ws_size,
                              hipStream_t stream)
{
  (void)in_sizes; (void)n_in; (void)out_size; (void)ws_size;
  const float* x    = (const float*)d_in[0];
  const float* W1   = (const float*)d_in[1];
  const float* b1   = (const float*)d_in[2];
  const float* W2   = (const float*)d_in[3];
  const float* b2   = (const float*)d_in[4];
  const float* Wout = (const float*)d_in[5];
  const float* bout = (const float*)d_in[6];
  float* out = (float*)d_out;

  const int M = 8192, H = 2048, Din = 1024;
  const size_t MB = (size_t)1024 * 1024;

  char* ws = (char*)d_ws;
  // [0,32MB): fragment-native fp16 GEMM out (a1, later a2)
  _Float16* a_nat = (_Float16*)ws;
  // [32,64MB): packed fp16 A operand (16MB for G1's tanh(x); then 32MB for G2)
  _Float16* Apk = (_Float16*)(ws + 32 * MB);
  // [64,68MB): W1 packed; [68,76MB): W2 packed
  _Float16* W1p = (_Float16*)(ws + 64 * MB);
  _Float16* W2p = (_Float16*)(ws + 68 * MB);
  // [80MB,...): small arrays
  float* small = (float*)(ws + 80 * MB);
  float* colabs1  = small + 0 * H;
  float* colabs2  = small + 1 * H;
  float* thermal1 = small + 2 * H;
  float* thermal2 = small + 3 * H;
  float* tn1      = small + 4 * H;
  float* tn2      = small + 5 * H;
  float* foldb    = small + 6 * H;

  // fold_in keys: key(42) = (0,42); fold_in(key, d) = threefry(key, [0,d])
  uint32_t kn0a, kn0b, kp0a, kp0b, kn1a, kn1b, kp1a, kp1b;
  threefry2x32(0u, 42u, 0u, 0u, kn0a, kn0b);   // noise, layer 0
  threefry2x32(0u, 42u, 0u, 1u, kp0a, kp0b);   // phase, layer 0
  threefry2x32(0u, 42u, 0u, 2u, kn1a, kn1b);   // noise, layer 1
  threefry2x32(0u, 42u, 0u, 3u, kp1a, kp1b);   // phase, layer 1

  hipMemsetAsync(colabs1, 0, 2 * H * sizeof(float), stream);

  // packs (kshift = log2(K/32))
  pack_plane<<<1024, 256, 0, stream>>>(W1, W1p, H, Din, 5, 0);
  pack_plane<<<2048, 256, 0, stream>>>(W2, W2p, H, H, 6, 0);
  pack_plane<<<2048, 256, 0, stream>>>(x, Apk, M, Din, 5, 1);

  const int nblk = (M / BM) * (H / BN);   // 64*16 = 1024 (multiple of 8)
  gemm_f16<<<nblk, 256, 0, stream>>>(Apk, W1p, b1, a_nat, colabs1,
                                     M, H, Din, kn0a, kn0b);
  thermal_tn<<<H / 256, 256, 0, stream>>>(colabs1, nullptr, thermal1, tn1, 0);
  bias_fold<<<H / 4, 256, 0, stream>>>(tn1, W2, b2, foldb, H);
  coherence_pack_small<<<2048, 256, 0, stream>>>(a_nat, tn1, Apk,
                                                 kp0a, kp0b, M, H, 6);
  gemm_f16<<<nblk, 256, 0, stream>>>(Apk, W2p, foldb, a_nat, colabs2,
                                     M, H, H, kn1a, kn1b);
  thermal_tn<<<H / 256, 256, 0, stream>>>(colabs2, thermal1, thermal2, tn2, 1);
  final_out<<<M / 4, 256, 0, stream>>>(a_nat, tn2, Wout, bout, out, kp1a, kp1b);
}

// Round 10
// 419.436 us; speedup vs baseline: 1.0428x; 1.0428x over previous
//
#include <hip/hip_runtime.h>
#include <stdint.h>
#include <math.h>

#define NOISE_LEVEL 0.02f
#define CROSSTALK   0.05f
#define COHERENCE   0.03f

typedef _Float16 half8 __attribute__((ext_vector_type(8)));
typedef _Float16 half4 __attribute__((ext_vector_type(4)));
typedef __attribute__((ext_vector_type(4))) float f32x4;

#define TF_ROUND(x0,x1,R) { x0 += x1; x1 = ((x1 << (R)) | (x1 >> (32-(R)))); x1 ^= x0; }

__host__ __device__ inline void threefry2x32(uint32_t k0, uint32_t k1,
                                             uint32_t x0, uint32_t x1,
                                             uint32_t& o0, uint32_t& o1)
{
  uint32_t ks2 = k0 ^ k1 ^ 0x1BD11BDAu;
  x0 += k0; x1 += k1;
  TF_ROUND(x0,x1,13) TF_ROUND(x0,x1,15) TF_ROUND(x0,x1,26) TF_ROUND(x0,x1,6)
  x0 += k1; x1 += ks2 + 1u;
  TF_ROUND(x0,x1,17) TF_ROUND(x0,x1,29) TF_ROUND(x0,x1,16) TF_ROUND(x0,x1,24)
  x0 += ks2; x1 += k0 + 2u;
  TF_ROUND(x0,x1,13) TF_ROUND(x0,x1,15) TF_ROUND(x0,x1,26) TF_ROUND(x0,x1,6)
  x0 += k0; x1 += k1 + 3u;
  TF_ROUND(x0,x1,17) TF_ROUND(x0,x1,29) TF_ROUND(x0,x1,16) TF_ROUND(x0,x1,24)
  x0 += k1; x1 += ks2 + 4u;
  TF_ROUND(x0,x1,13) TF_ROUND(x0,x1,15) TF_ROUND(x0,x1,26) TF_ROUND(x0,x1,6)
  o0 = x0 + ks2; o1 = x1 + k0 + 5u;
}

// threefry_partitionable bits for 32-bit draws: XOR of the two output words.
__device__ inline uint32_t jax_bits(uint32_t k0, uint32_t k1, uint32_t idx)
{
  uint32_t o0, o1; threefry2x32(k0, k1, 0u, idx, o0, o1); return o0 ^ o1;
}

// JAX random.normal(float32): u ~ uniform[-0.99999994, 1); n = sqrt(2)*erfinv(u)
__device__ inline float jax_normal(uint32_t k0, uint32_t k1, uint32_t idx)
{
  uint32_t bits = jax_bits(k0, k1, idx);
  float f = __uint_as_float((bits >> 9) | 0x3f800000u) - 1.0f;   // [0,1)
  float u = fmaf(f, 2.0f, -0.99999994f);
  u = fmaxf(-0.99999994f, u);
  float w = -__logf(fmaf(-u, u, 1.0f));
  float wl = w - 2.5f;
  float p = 2.81022636e-08f;
  p = fmaf(p, wl, 3.43273939e-07f);
  p = fmaf(p, wl, -3.5233877e-06f);
  p = fmaf(p, wl, -4.39150654e-06f);
  p = fmaf(p, wl, 0.00021858087f);
  p = fmaf(p, wl, -0.00125372503f);
  p = fmaf(p, wl, -0.00417768164f);
  p = fmaf(p, wl, 0.246640727f);
  p = fmaf(p, wl, 1.50140941f);
  if (__any(w >= 5.0f)) {
    float ws = sqrtf(w) - 3.0f;
    float q = -0.000200214257f;
    q = fmaf(q, ws, 0.000100950558f);
    q = fmaf(q, ws, 0.00134934322f);
    q = fmaf(q, ws, -0.00367342844f);
    q = fmaf(q, ws, 0.00573950773f);
    q = fmaf(q, ws, -0.0076224613f);
    q = fmaf(q, ws, 0.00943887047f);
    q = fmaf(q, ws, 1.00167406f);
    q = fmaf(q, ws, 2.83297682f);
    p = (w >= 5.0f) ? q : p;
  }
  return 1.41421354f * (p * u);
}

__device__ inline float cos_small(float p)
{
  float p2 = p * p;
  return 1.0f + p2 * (-0.5f + p2 * (4.16666679e-02f + p2 * (-1.38888892e-03f)));
}

// exact-algebra tanh via fast exp; abs err <= ~1.2e-7, inf-safe.
__device__ inline float tanh_fast(float x)
{
  float ax = fabsf(x);
  float e = __expf(2.0f * ax);
  float r = 1.0f - 2.0f / (e + 1.0f);
  return copysignf(r, x);
}

// ---------------------------------------------------------------------------
// Packed fp16 operand layout (BK=32, row-block RB = 1<<rbbits):
//   tile (rb,kt) occupies RB*32 halves at (rb*ktiles + kt)*RB*32,
//   internally [kq(4)][row(RB)][8].
// A planes use RB=128 (rbbits=7); B/W planes use RB=64 (rbbits=6) = BN.
// ---------------------------------------------------------------------------

__global__ __launch_bounds__(256)
void pack_plane(const float* __restrict__ in, _Float16* __restrict__ out,
                int R, int K, int kshift, int rbbits, int do_tanh)
{
  const int nslots = R * (K >> 3);
  const int ktm = (K >> 5) - 1;
  const int slotbits = rbbits + 2;
  int g = blockIdx.x * 256 + threadIdx.x;
  const int stride = gridDim.x * 256;
  for (; g < nslots; g += stride) {
    int tile = g >> slotbits;
    int s = g & ((1 << slotbits) - 1);
    int kq = s >> rbbits, row = s & ((1 << rbbits) - 1);
    int rb = tile >> kshift, kt = tile & ktm;
    int r = (rb << rbbits) + row;
    int k = kt * 32 + kq * 8;
    const float* src = in + (size_t)r * K + k;
    float4 v0 = *(const float4*)src;
    float4 v1 = *(const float4*)(src + 4);
    float xs[8] = {v0.x, v0.y, v0.z, v0.w, v1.x, v1.y, v1.z, v1.w};
    half8 h;
    #pragma unroll
    for (int e = 0; e < 8; ++e) {
      float x = do_tanh ? tanh_fast(xs[e]) : xs[e];
      h[e] = (_Float16)x;
    }
    *(half8*)&out[(size_t)g * 8] = h;
  }
}

// fragment-native fp16 output layout for 128x64 C blocks (N=2048, nbn=32):
//   idx = ((blk*4 + w)*32 + fn*16 + fm*4 + j)*64 + lane
__device__ __forceinline__ size_t cnat_idx(int r, int c)
{
  int bm = r >> 7, bn = c >> 6, rr = r & 127, cc = c & 63;
  int w = ((rr >> 6) << 1) | (cc >> 5);
  int fm = (rr >> 4) & 3, lg = (rr >> 2) & 3, j = rr & 3;
  int fn = (cc >> 4) & 1, lm = cc & 15;
  return (((size_t)(bm * 32 + bn) * 4 + w) * 32 + fn * 16 + fm * 4 + j) * 64
         + lg * 16 + lm;
}

// coherence + thermal-decompose + pack: reads G1 out (fragment-native fp16),
// full = (x + tn) with phase interference; small = full - tn[col] ->
// A-packed fp16 (RB=128).
__global__ __launch_bounds__(256)
void coherence_pack_small(const _Float16* __restrict__ xn, const float* __restrict__ tn,
                          _Float16* __restrict__ out,
                          uint32_t pk0, uint32_t pk1, int R, int K, int kshift)
{
  const int nslots = R * (K >> 3);
  const int ktm = (K >> 5) - 1;
  int g = blockIdx.x * 256 + threadIdx.x;
  const int stride = gridDim.x * 256;
  for (; g < nslots; g += stride) {
    int tile = g >> 9;
    int s = g & 511;
    int kq = s >> 7, row = s & 127;
    int rb = tile >> kshift, kt = tile & ktm;
    int r = rb * 128 + row;
    int k = kt * 32 + kq * 8;
    half8 xv = *(const half8*)&xn[cnat_idx(r, k)];   // 8 consecutive cols
    float4 t0 = *(const float4*)&tn[k];
    float4 t1 = *(const float4*)&tn[k + 4];
    float ts[8] = {t0.x, t0.y, t0.z, t0.w, t1.x, t1.y, t1.z, t1.w};
    uint32_t fb = (uint32_t)(r * K + k);
    half8 h;
    #pragma unroll
    for (int e = 0; e < 8; ++e) {
      float vv = (float)xv[e] + ts[e];
      float ph = COHERENCE * jax_normal(pk0, pk1, fb + e);
      float cp = cos_small(ph);
      float xvv = vv + (vv * cp - vv) * COHERENCE;
      h[e] = (_Float16)(xvv - ts[e]);
    }
    *(half8*)&out[(size_t)g * 8] = h;
  }
}

// bias_fold: fold[j] = b[j] + sum_h tn[h] * W[j,h]   (fp32, one wave per j)
__global__ __launch_bounds__(256)
void bias_fold(const float* __restrict__ tn, const float* __restrict__ W,
               const float* __restrict__ b, float* __restrict__ fold, int K)
{
  const int wid = threadIdx.x >> 6;
  const int lane = threadIdx.x & 63;
  const int j = blockIdx.x * 4 + wid;
  const float* row = W + (size_t)j * K;
  float s = 0.0f;
  for (int h = lane; h < K; h += 64) s = fmaf(tn[h], row[h], s);
  #pragma unroll
  for (int off = 32; off > 0; off >>= 1) s += __shfl_down(s, off);
  if (lane == 0) fold[j] = b[j] + s;
}

// ---------------------------------------------------------------------------
// fp16 MFMA GEMM, BM=128 x BN=64 tiles -> 2048 blocks (8/CU available), LDS
// 24 KiB, __launch_bounds__(256,5): attacks the R7-R9 plateau (latency-bound
// at 4 blocks/CU, occupancy 20%). 4 waves, each owns 64x32 (4x2 frags).
// Noise normals held as fp16 regs (8 x half4) to fit the 102-VGPR cap.
// MFMA k-order per output identical to R9.
// ---------------------------------------------------------------------------
#define BM 128
#define BN 64
#define ATILE 4096            // halves per A tile (128*32)
#define BTILE 2048            // halves per B tile (64*32)
#define BUFH  (ATILE + BTILE) // 6144 halves per buffer

__device__ __forceinline__ f32x4 noise_group(int g, int blockM, int blockN,
                                             int wr, int wc, int lg, int lm,
                                             int N, uint32_t k0, uint32_t k1)
{
  int fn = g >> 2, fm = g & 3;
  int gr0 = blockM + wr * 64 + fm * 16 + lg * 4;
  int gc  = blockN + wc * 32 + fn * 16 + lm;
  f32x4 r;
  #pragma unroll
  for (int j = 0; j < 4; ++j)
    r[j] = jax_normal(k0, k1, (uint32_t)((gr0 + j) * N + gc));
  return r;
}

__global__ __launch_bounds__(256, 5)
void gemm_f16(const _Float16* __restrict__ Ap, const _Float16* __restrict__ Bp,
              const float* __restrict__ bias, _Float16* __restrict__ outn,
              float* __restrict__ colabs, int M, int N, int K,
              uint32_t nk0, uint32_t nk1)
{
  __shared__ __align__(16) _Float16 lds[2 * BUFH];   // 24 KiB

  const int t = threadIdx.x;
  const int nwg = gridDim.x;
  const int wg = (blockIdx.x & 7) * (nwg >> 3) + (blockIdx.x >> 3);
  const int nbn = N / BN;              // 32
  const int bn = wg & (nbn - 1);       // bn-minor: consecutive wgs share A panel
  const int bm = wg / nbn;
  const int blockM = bm * BM, blockN = bn * BN;

  const int lane = t & 63;
  const int w = t >> 6;
  const int wr = w >> 1, wc = w & 1;
  const int lm = lane & 15, lg = lane >> 4;

  const int ktiles = K >> 5;

  // staging: 12 x 1KB global_load_lds per k-tile; wave w issues loads 3w..3w+2
  const _Float16* gsrc[3];
  int gstride[3];
  _Float16* ldst[3];
  #pragma unroll
  for (int i = 0; i < 3; ++i) {
    int l = w * 3 + i;
    if (l < 8) {
      gsrc[i] = Ap + ((size_t)bm * ktiles) * ATILE + l * 512 + lane * 8;
      gstride[i] = ATILE;
      ldst[i] = lds + l * 512;
    } else {
      gsrc[i] = Bp + ((size_t)bn * ktiles) * BTILE + (l - 8) * 512 + lane * 8;
      gstride[i] = BTILE;
      ldst[i] = lds + ATILE + (l - 8) * 512;
    }
  }

#define STAGE(buf, kt_) {                                                      \
    _Pragma("unroll")                                                          \
    for (int i = 0; i < 3; ++i)                                                \
      __builtin_amdgcn_global_load_lds(                                        \
          (const void*)(gsrc[i] + (size_t)(kt_) * gstride[i]),                 \
          (void*)(ldst[i] + (buf) * BUFH), 16, 0, 0);                          \
  }

  f32x4 acc[4][2];
  #pragma unroll
  for (int i = 0; i < 4; ++i)
    #pragma unroll
    for (int j = 0; j < 2; ++j) acc[i][j] = 0.0f;

  half4 nh0 = 0, nh1 = 0, nh2 = 0, nh3 = 0, nh4 = 0, nh5 = 0, nh6 = 0, nh7 = 0;

  const int nk = ktiles;               // 32 (G1) or 64 (G2)
  STAGE(0, 0);
  __syncthreads();
  int cur = 0;

  for (int kt = 0; kt < nk; ++kt) {
    if (kt + 1 < nk) STAGE(cur ^ 1, kt + 1);

    const _Float16* base = lds + cur * BUFH;
    half8 fa[4], fb[2];
    #pragma unroll
    for (int fm = 0; fm < 4; ++fm)
      fa[fm] = *(const half8*)(base + lg * 1024 + (wr * 64 + fm * 16 + lm) * 8);
    #pragma unroll
    for (int fn = 0; fn < 2; ++fn)
      fb[fn] = *(const half8*)(base + ATILE + lg * 512 + (wc * 32 + fn * 16 + lm) * 8);
    #pragma unroll
    for (int fm = 0; fm < 4; ++fm)
      #pragma unroll
      for (int fn = 0; fn < 2; ++fn)
        acc[fm][fn] = __builtin_amdgcn_mfma_f32_16x16x32_f16(fa[fm], fb[fn], acc[fm][fn], 0, 0, 0);

    // in-loop RNG: one 4-normal group per step (first 8 steps), fp16 regs.
    if (kt < 8) {
      f32x4 v = noise_group(kt, blockM, blockN, wr, wc, lg, lm, N, nk0, nk1);
      half4 hv;
      #pragma unroll
      for (int j = 0; j < 4; ++j) hv[j] = (_Float16)v[j];
      switch (kt) {
        case 0: nh0 = hv; break;  case 1: nh1 = hv; break;
        case 2: nh2 = hv; break;  case 3: nh3 = hv; break;
        case 4: nh4 = hv; break;  case 5: nh5 = hv; break;
        case 6: nh6 = hv; break;  default: nh7 = hv; break;
      }
    }

    __syncthreads();
    cur ^= 1;
  }

  // epilogue: fragment-native stores (64 lanes x 2B = one 128B line each)
  const size_t obase = (((size_t)(bm * nbn + bn) * 4 + w) * 32) * 64 + lane;

#define EPI_STORE(fm_, fn_, NZV)                                               \
    _Pragma("unroll")                                                          \
    for (int j = 0; j < 4; ++j) {                                              \
      float v = tanh_fast(acc[fm_][fn_][j] + bv) + NOISE_LEVEL * (float)NZV[j];\
      outn[obase + (size_t)((fn_)*16 + (fm_)*4 + j) * 64] = (_Float16)v;       \
      cp += fabsf(v);                                                          \
    }

#define EPI_FN(fn_, NZA, NZB, NZC, NZD) {                                      \
    const int gc = blockN + wc * 32 + (fn_)*16 + lm;                           \
    const float bv = bias[gc];                                                 \
    float cp = 0.0f;                                                           \
    EPI_STORE(0, fn_, NZA) EPI_STORE(1, fn_, NZB)                              \
    EPI_STORE(2, fn_, NZC) EPI_STORE(3, fn_, NZD)                              \
    cp += __shfl_xor(cp, 16);                                                  \
    cp += __shfl_xor(cp, 32);                                                  \
    if (lg == 0) atomicAdd(&colabs[gc], cp);                                   \
  }

  EPI_FN(0, nh0, nh1, nh2, nh3)
  EPI_FN(1, nh4, nh5, nh6, nh7)
#undef EPI_FN
#undef EPI_STORE
#undef STAGE
}

// ---------------------------------------------------------------------------
// thermal = 0.7*prev + 0.3*(colabs*CROSSTALK); tn[i] = CROSSTALK * sum thermal[j]/(i-j)^2
// ---------------------------------------------------------------------------
__global__ __launch_bounds__(256)
void thermal_tn(const float* __restrict__ colabs, const float* __restrict__ prev_thermal,
                float* __restrict__ thermal_out, float* __restrict__ tn_out, int has_prev)
{
  __shared__ float th[2048];
  __shared__ float inv[2048];
  const int t = threadIdx.x;
  for (int j = t; j < 2048; j += 256) {
    float lt = colabs[j] * CROSSTALK;
    float pv = has_prev ? prev_thermal[j] : 0.0f;
    th[j] = 0.7f * pv + 0.3f * lt;
    float d = (float)j;
    inv[j] = (j == 0) ? 0.0f : 1.0f / (d * d);
  }
  __syncthreads();
  const int i = blockIdx.x * 256 + t;
  float s = 0.0f;
  #pragma unroll 4
  for (int j = 0; j < 2048; ++j) {
    int d = i - j; d = d < 0 ? -d : d;
    s += th[j] * inv[d];
  }
  tn_out[i] = s * CROSSTALK;
  thermal_out[i] = th[i];
}

// ---------------------------------------------------------------------------
// Final: x2 = (a2 + tn2) with coherence; out[b,:] = x2[b,:] @ Wout^T + bout.
// a2 is fragment-native fp16 (128x64 blocks).
// ---------------------------------------------------------------------------
__global__ __launch_bounds__(256)
void final_out(const _Float16* __restrict__ a2n, const float* __restrict__ tn2,
               const float* __restrict__ Wout, const float* __restrict__ bout,
               float* __restrict__ out, uint32_t pk0, uint32_t pk1)
{
  const int wave = threadIdx.x >> 6;
  const int lane = threadIdx.x & 63;
  const int b = blockIdx.x * 4 + wave;
  float acc0 = 0.0f, acc1 = 0.0f;
  #pragma unroll
  for (int i = 0; i < 8; ++i) {
    int h = lane * 4 + i * 256;
    half4 v4 = *(const half4*)&a2n[cnat_idx(b, h)];
    float4 tv = *(const float4*)&tn2[h];
    float4 w0 = *(const float4*)&Wout[h];
    float4 w1 = *(const float4*)&Wout[2048 + h];
    float xs[4]  = {(float)v4[0] + tv.x, (float)v4[1] + tv.y,
                    (float)v4[2] + tv.z, (float)v4[3] + tv.w};
    float w0s[4] = {w0.x, w0.y, w0.z, w0.w};
    float w1s[4] = {w1.x, w1.y, w1.z, w1.w};
    uint32_t fb = (uint32_t)(b * 2048 + h);
    #pragma unroll
    for (int e = 0; e < 4; ++e) {
      float ph = COHERENCE * jax_normal(pk0, pk1, fb + e);
      float cp = cos_small(ph);
      float xv = xs[e] + (xs[e] * cp - xs[e]) * COHERENCE;
      acc0 = fmaf(xv, w0s[e], acc0);
      acc1 = fmaf(xv, w1s[e], acc1);
    }
  }
  #pragma unroll
  for (int off = 32; off > 0; off >>= 1) {
    acc0 += __shfl_down(acc0, off);
    acc1 += __shfl_down(acc1, off);
  }
  if (lane == 0) {
    out[(size_t)b * 2 + 0] = acc0 + bout[0];
    out[(size_t)b * 2 + 1] = acc1 + bout[1];
  }
}

extern "C" void kernel_launch(void* const* d_in, const int* in_sizes, int n_in,
                              void* d_out, int out_size, void* d_ws, size_t ws_size,
                              hipStream_t stream)
{
  (void)in_sizes; (void)n_in; (void)out_size; (void)ws_size;
  const float* x    = (const float*)d_in[0];
  const float* W1   = (const float*)d_in[1];
  const float* b1   = (const float*)d_in[2];
  const float* W2   = (const float*)d_in[3];
  const float* b2   = (const float*)d_in[4];
  const float* Wout = (const float*)d_in[5];
  const float* bout = (const float*)d_in[6];
  float* out = (float*)d_out;

  const int M = 8192, H = 2048, Din = 1024;
  const size_t MB = (size_t)1024 * 1024;

  char* ws = (char*)d_ws;
  // [0,32MB): fragment-native fp16 GEMM out (a1, later a2)
  _Float16* a_nat = (_Float16*)ws;
  // [32,64MB): A-packed fp16 operand (16MB for G1's tanh(x); then 32MB for G2)
  _Float16* Apk = (_Float16*)(ws + 32 * MB);
  // [64,68MB): W1 packed (RB=64); [68,76MB): W2 packed (RB=64)
  _Float16* W1p = (_Float16*)(ws + 64 * MB);
  _Float16* W2p = (_Float16*)(ws + 68 * MB);
  // [80MB,...): small arrays
  float* small = (float*)(ws + 80 * MB);
  float* colabs1  = small + 0 * H;
  float* colabs2  = small + 1 * H;
  float* thermal1 = small + 2 * H;
  float* thermal2 = small + 3 * H;
  float* tn1      = small + 4 * H;
  float* tn2      = small + 5 * H;
  float* foldb    = small + 6 * H;

  // fold_in keys: key(42) = (0,42); fold_in(key, d) = threefry(key, [0,d])
  uint32_t kn0a, kn0b, kp0a, kp0b, kn1a, kn1b, kp1a, kp1b;
  threefry2x32(0u, 42u, 0u, 0u, kn0a, kn0b);   // noise, layer 0
  threefry2x32(0u, 42u, 0u, 1u, kp0a, kp0b);   // phase, layer 0
  threefry2x32(0u, 42u, 0u, 2u, kn1a, kn1b);   // noise, layer 1
  threefry2x32(0u, 42u, 0u, 3u, kp1a, kp1b);   // phase, layer 1

  hipMemsetAsync(colabs1, 0, 2 * H * sizeof(float), stream);

  // packs: A planes rbbits=7, W planes rbbits=6 (= BN); kshift = log2(K/32)
  pack_plane<<<1024, 256, 0, stream>>>(W1, W1p, H, Din, 5, 6, 0);
  pack_plane<<<2048, 256, 0, stream>>>(W2, W2p, H, H, 6, 6, 0);
  pack_plane<<<2048, 256, 0, stream>>>(x, Apk, M, Din, 5, 7, 1);

  const int nblk = (M / BM) * (H / BN);   // 64*32 = 2048 (multiple of 8)
  gemm_f16<<<nblk, 256, 0, stream>>>(Apk, W1p, b1, a_nat, colabs1,
                                     M, H, Din, kn0a, kn0b);
  thermal_tn<<<H / 256, 256, 0, stream>>>(colabs1, nullptr, thermal1, tn1, 0);
  bias_fold<<<H / 4, 256, 0, stream>>>(tn1, W2, b2, foldb, H);
  coherence_pack_small<<<2048, 256, 0, stream>>>(a_nat, tn1, Apk,
                                                 kp0a, kp0b, M, H, 6);
  gemm_f16<<<nblk, 256, 0, stream>>>(Apk, W2p, foldb, a_nat, colabs2,
                                     M, H, H, kn1a, kn1b);
  thermal_tn<<<H / 256, 256, 0, stream>>>(colabs2, thermal1, thermal2, tn2, 1);
  final_out<<<M / 4, 256, 0, stream>>>(a_nat, tn2, Wout, bout, out, kp1a, kp1b);
}

// Round 11
// 360.628 us; speedup vs baseline: 1.2129x; 1.1631x over previous
//
#include <hip/hip_runtime.h>
#include <stdint.h>
#include <math.h>

#define NOISE_LEVEL 0.02f
#define CROSSTALK   0.05f
#define COHERENCE   0.03f
// coherence factor with E[n^2]=1: 1 + 0.03*(exp(-0.03^2/2)-1) = 1 - 1.3497e-5
#define F_COH 0.99998650f

typedef _Float16 half8 __attribute__((ext_vector_type(8)));
typedef _Float16 half4 __attribute__((ext_vector_type(4)));
typedef __attribute__((ext_vector_type(4))) float f32x4;

#define TF_ROUND(x0,x1,R) { x0 += x1; x1 = ((x1 << (R)) | (x1 >> (32-(R)))); x1 ^= x0; }

__host__ __device__ inline void threefry2x32(uint32_t k0, uint32_t k1,
                                             uint32_t x0, uint32_t x1,
                                             uint32_t& o0, uint32_t& o1)
{
  uint32_t ks2 = k0 ^ k1 ^ 0x1BD11BDAu;
  x0 += k0; x1 += k1;
  TF_ROUND(x0,x1,13) TF_ROUND(x0,x1,15) TF_ROUND(x0,x1,26) TF_ROUND(x0,x1,6)
  x0 += k1; x1 += ks2 + 1u;
  TF_ROUND(x0,x1,17) TF_ROUND(x0,x1,29) TF_ROUND(x0,x1,16) TF_ROUND(x0,x1,24)
  x0 += ks2; x1 += k0 + 2u;
  TF_ROUND(x0,x1,13) TF_ROUND(x0,x1,15) TF_ROUND(x0,x1,26) TF_ROUND(x0,x1,6)
  x0 += k0; x1 += k1 + 3u;
  TF_ROUND(x0,x1,17) TF_ROUND(x0,x1,29) TF_ROUND(x0,x1,16) TF_ROUND(x0,x1,24)
  x0 += k1; x1 += ks2 + 4u;
  TF_ROUND(x0,x1,13) TF_ROUND(x0,x1,15) TF_ROUND(x0,x1,26) TF_ROUND(x0,x1,6)
  o0 = x0 + ks2; o1 = x1 + k0 + 5u;
}

// threefry_partitionable bits for 32-bit draws: XOR of the two output words.
__device__ inline uint32_t jax_bits(uint32_t k0, uint32_t k1, uint32_t idx)
{
  uint32_t o0, o1; threefry2x32(k0, k1, 0u, idx, o0, o1); return o0 ^ o1;
}

// JAX random.normal(float32): u ~ uniform[-0.99999994, 1); n = sqrt(2)*erfinv(u)
__device__ inline float jax_normal(uint32_t k0, uint32_t k1, uint32_t idx)
{
  uint32_t bits = jax_bits(k0, k1, idx);
  float f = __uint_as_float((bits >> 9) | 0x3f800000u) - 1.0f;   // [0,1)
  float u = fmaf(f, 2.0f, -0.99999994f);
  u = fmaxf(-0.99999994f, u);
  float w = -__logf(fmaf(-u, u, 1.0f));
  float wl = w - 2.5f;
  float p = 2.81022636e-08f;
  p = fmaf(p, wl, 3.43273939e-07f);
  p = fmaf(p, wl, -3.5233877e-06f);
  p = fmaf(p, wl, -4.39150654e-06f);
  p = fmaf(p, wl, 0.00021858087f);
  p = fmaf(p, wl, -0.00125372503f);
  p = fmaf(p, wl, -0.00417768164f);
  p = fmaf(p, wl, 0.246640727f);
  p = fmaf(p, wl, 1.50140941f);
  if (__any(w >= 5.0f)) {
    float ws = sqrtf(w) - 3.0f;
    float q = -0.000200214257f;
    q = fmaf(q, ws, 0.000100950558f);
    q = fmaf(q, ws, 0.00134934322f);
    q = fmaf(q, ws, -0.00367342844f);
    q = fmaf(q, ws, 0.00573950773f);
    q = fmaf(q, ws, -0.0076224613f);
    q = fmaf(q, ws, 0.00943887047f);
    q = fmaf(q, ws, 1.00167406f);
    q = fmaf(q, ws, 2.83297682f);
    p = (w >= 5.0f) ? q : p;
  }
  return 1.41421354f * (p * u);
}

// exact-algebra tanh via fast exp; abs err <= ~1.2e-7, inf-safe.
__device__ inline float tanh_fast(float x)
{
  float ax = fabsf(x);
  float e = __expf(2.0f * ax);
  float r = 1.0f - 2.0f / (e + 1.0f);
  return copysignf(r, x);
}

// ---------------------------------------------------------------------------
// Packed fp16 operand layout (BK=32, row-block RB = 1<<rbbits):
//   tile (rb,kt) occupies RB*32 halves at (rb*ktiles + kt)*RB*32,
//   internally [kq(4)][row(RB)][8].
// A planes: RB=128 (rbbits=7); B/W planes: RB=64 (rbbits=6) = BN.
// ---------------------------------------------------------------------------
__global__ __launch_bounds__(256)
void pack_plane(const float* __restrict__ in, _Float16* __restrict__ out,
                int R, int K, int kshift, int rbbits, int do_tanh)
{
  const int nslots = R * (K >> 3);
  const int ktm = (K >> 5) - 1;
  const int slotbits = rbbits + 2;
  int g = blockIdx.x * 256 + threadIdx.x;
  const int stride = gridDim.x * 256;
  for (; g < nslots; g += stride) {
    int tile = g >> slotbits;
    int s = g & ((1 << slotbits) - 1);
    int kq = s >> rbbits, row = s & ((1 << rbbits) - 1);
    int rb = tile >> kshift, kt = tile & ktm;
    int r = (rb << rbbits) + row;
    int k = kt * 32 + kq * 8;
    const float* src = in + (size_t)r * K + k;
    float4 v0 = *(const float4*)src;
    float4 v1 = *(const float4*)(src + 4);
    float xs[8] = {v0.x, v0.y, v0.z, v0.w, v1.x, v1.y, v1.z, v1.w};
    half8 h;
    #pragma unroll
    for (int e = 0; e < 8; ++e) {
      float x = do_tanh ? tanh_fast(xs[e]) : xs[e];
      h[e] = (_Float16)x;
    }
    *(half8*)&out[(size_t)g * 8] = h;
  }
}

// fragment-native fp16 output layout for 128x64 C blocks (N=2048, nbn=32):
//   idx = ((blk*4 + w)*32 + fn*16 + fm*4 + j)*64 + lane
__device__ __forceinline__ size_t cnat_idx(int r, int c)
{
  int bm = r >> 7, bn = c >> 6, rr = r & 127, cc = c & 63;
  int w = ((rr >> 6) << 1) | (cc >> 5);
  int fm = (rr >> 4) & 3, lg = (rr >> 2) & 3, j = rr & 3;
  int fn = (cc >> 4) & 1, lm = cc & 15;
  return (((size_t)(bm * 32 + bn) * 4 + w) * 32 + fn * 16 + fm * 4 + j) * 64
         + lg * 16 + lm;
}

// bias_fold: fold[j] = b[j] + scale * sum_h tn[h] * W[j,h]  (fp32; one wave/j)
__global__ __launch_bounds__(256)
void bias_fold(const float* __restrict__ tn, const float* __restrict__ W,
               const float* __restrict__ b, float* __restrict__ fold,
               int K, int nrows, float scale)
{
  const int wid = threadIdx.x >> 6;
  const int lane = threadIdx.x & 63;
  const int j = blockIdx.x * 4 + wid;
  if (j >= nrows) return;
  const float* row = W + (size_t)j * K;
  float s = 0.0f;
  for (int h = lane; h < K; h += 64) s = fmaf(tn[h], row[h], s);
  #pragma unroll
  for (int off = 32; off > 0; off >>= 1) s += __shfl_down(s, off);
  if (lane == 0) fold[j] = fmaf(scale, s, b[j]);
}

// ---------------------------------------------------------------------------
// fp16 MFMA GEMM, BM=128 x BN=64, BK=32, 4 waves, dbuf, in-loop noise RNG.
//   v = tanh(oscale*acc + bias) + 0.02*normal(key, r*N+c); colabs += sum|v|.
// OUTMODE 0: write v directly in the G2-A packed layout (K2=2048, ktiles=64)
//            - 16B-granule scatter, L2 write-merged (G1 uses this; its output
//            IS G2's A operand: coherence folded algebraically via F_COH).
// OUTMODE 1: fragment-native 128x64 layout (G2; final_out decodes).
// Block order: XCD region 16bm x 16bn, walked in 4bm x 8bn sub-chunks
// (A 2MB + W 2MB = 4MB = per-XCD L2) - attacks R10's 257MB L2-fill thrash.
// Grid must be 64 x 32 = 2048 blocks.
// ---------------------------------------------------------------------------
#define BM 128
#define BN 64
#define ATILE 4096            // halves per A tile (128*32)
#define BTILE 2048            // halves per B tile (64*32)
#define BUFH  (ATILE + BTILE)

__device__ __forceinline__ f32x4 noise_group(int g, int blockM, int blockN,
                                             int wr, int wc, int lg, int lm,
                                             int N, uint32_t k0, uint32_t k1)
{
  int fn = g >> 2, fm = g & 3;
  int gr0 = blockM + wr * 64 + fm * 16 + lg * 4;
  int gc  = blockN + wc * 32 + fn * 16 + lm;
  f32x4 r;
  #pragma unroll
  for (int j = 0; j < 4; ++j)
    r[j] = jax_normal(k0, k1, (uint32_t)((gr0 + j) * N + gc));
  return r;
}

template<int OUTMODE>
__global__ __launch_bounds__(256, 5)
void gemm_f16(const _Float16* __restrict__ Ap, const _Float16* __restrict__ Bp,
              const float* __restrict__ bias, _Float16* __restrict__ outn,
              float* __restrict__ colabs, int M, int N, int K, float oscale,
              uint32_t nk0, uint32_t nk1)
{
  __shared__ __align__(16) _Float16 lds[2 * BUFH];   // 24 KiB

  const int t = threadIdx.x;
  // XCD-region + L2-sub-chunk block order (grid = 64bm x 32bn, 8 XCDs)
  const int bid = blockIdx.x;
  const int xcd = bid & 7, p = bid >> 3;       // p in [0,256) per XCD
  const int s = p >> 5, q = p & 31;            // 8 sub-chunks of 32 blocks
  const int bm = ((xcd >> 1) << 4) + ((s >> 1) << 2) + (q >> 3);
  const int bn = ((xcd & 1) << 4) + ((s & 1) << 3) + (q & 7);
  const int blockM = bm * BM, blockN = bn * BN;

  const int lane = t & 63;
  const int w = t >> 6;
  const int wr = w >> 1, wc = w & 1;
  const int lm = lane & 15, lg = lane >> 4;

  const int ktiles = K >> 5;

  // staging: 12 x 1KB global_load_lds per k-tile; wave w issues loads 3w..3w+2
  const _Float16* gsrc[3];
  int gstride[3];
  _Float16* ldst[3];
  #pragma unroll
  for (int i = 0; i < 3; ++i) {
    int l = w * 3 + i;
    if (l < 8) {
      gsrc[i] = Ap + ((size_t)bm * ktiles) * ATILE + l * 512 + lane * 8;
      gstride[i] = ATILE;
      ldst[i] = lds + l * 512;
    } else {
      gsrc[i] = Bp + ((size_t)bn * ktiles) * BTILE + (l - 8) * 512 + lane * 8;
      gstride[i] = BTILE;
      ldst[i] = lds + ATILE + (l - 8) * 512;
    }
  }

#define STAGE(buf, kt_) {                                                      \
    _Pragma("unroll")                                                          \
    for (int i = 0; i < 3; ++i)                                                \
      __builtin_amdgcn_global_load_lds(                                        \
          (const void*)(gsrc[i] + (size_t)(kt_) * gstride[i]),                 \
          (void*)(ldst[i] + (buf) * BUFH), 16, 0, 0);                          \
  }

  f32x4 acc[4][2];
  #pragma unroll
  for (int i = 0; i < 4; ++i)
    #pragma unroll
    for (int j = 0; j < 2; ++j) acc[i][j] = 0.0f;

  half4 nh0 = 0, nh1 = 0, nh2 = 0, nh3 = 0, nh4 = 0, nh5 = 0, nh6 = 0, nh7 = 0;

  const int nk = ktiles;               // 32 (G1) or 64 (G2)
  STAGE(0, 0);
  __syncthreads();
  int cur = 0;

  for (int kt = 0; kt < nk; ++kt) {
    if (kt + 1 < nk) STAGE(cur ^ 1, kt + 1);

    const _Float16* base = lds + cur * BUFH;
    half8 fa[4], fb[2];
    #pragma unroll
    for (int fm = 0; fm < 4; ++fm)
      fa[fm] = *(const half8*)(base + lg * 1024 + (wr * 64 + fm * 16 + lm) * 8);
    #pragma unroll
    for (int fn = 0; fn < 2; ++fn)
      fb[fn] = *(const half8*)(base + ATILE + lg * 512 + (wc * 32 + fn * 16 + lm) * 8);
    #pragma unroll
    for (int fm = 0; fm < 4; ++fm)
      #pragma unroll
      for (int fn = 0; fn < 2; ++fn)
        acc[fm][fn] = __builtin_amdgcn_mfma_f32_16x16x32_f16(fa[fm], fb[fn], acc[fm][fn], 0, 0, 0);

    // in-loop RNG: one 4-normal group per step (first 8 steps), fp16 regs.
    if (kt < 8) {
      f32x4 v = noise_group(kt, blockM, blockN, wr, wc, lg, lm, N, nk0, nk1);
      half4 hv;
      #pragma unroll
      for (int j = 0; j < 4; ++j) hv[j] = (_Float16)v[j];
      switch (kt) {
        case 0: nh0 = hv; break;  case 1: nh1 = hv; break;
        case 2: nh2 = hv; break;  case 3: nh3 = hv; break;
        case 4: nh4 = hv; break;  case 5: nh5 = hv; break;
        case 6: nh6 = hv; break;  default: nh7 = hv; break;
      }
    }

    __syncthreads();
    cur ^= 1;
  }

  // epilogue
  // OUTMODE 0: idx = (bm*64 + bn*2 + wc)*4096 + (fn*2 + lm>>3)*1024
  //                  + (wr*64+fm*16+lg*4+j)*8 + (lm&7)
  const size_t wbase0 = ((size_t)(bm * 64 + bn * 2 + wc)) * 4096
                        + (size_t)(lm >> 3) * 1024 + (lm & 7);
  const size_t obase1 = (((size_t)(bm * 32 + bn) * 4 + w) * 32) * 64 + lane;

#define EPI_STORE(fm_, fn_, NZV)                                               \
    _Pragma("unroll")                                                          \
    for (int j = 0; j < 4; ++j) {                                              \
      float v = tanh_fast(fmaf(oscale, acc[fm_][fn_][j], bv))                  \
                + NOISE_LEVEL * (float)NZV[j];                                 \
      if (OUTMODE == 0)                                                        \
        outn[wbase0 + (fn_)*2048 + (size_t)(wr*64 + (fm_)*16 + lg*4 + j)*8]    \
            = (_Float16)v;                                                     \
      else                                                                     \
        outn[obase1 + (size_t)((fn_)*16 + (fm_)*4 + j) * 64] = (_Float16)v;    \
      cp += fabsf(v);                                                          \
    }

#define EPI_FN(fn_, NZA, NZB, NZC, NZD) {                                      \
    const int gc = blockN + wc * 32 + (fn_)*16 + lm;                           \
    const float bv = bias[gc];                                                 \
    float cp = 0.0f;                                                           \
    EPI_STORE(0, fn_, NZA) EPI_STORE(1, fn_, NZB)                              \
    EPI_STORE(2, fn_, NZC) EPI_STORE(3, fn_, NZD)                              \
    cp += __shfl_xor(cp, 16);                                                  \
    cp += __shfl_xor(cp, 32);                                                  \
    if (lg == 0) atomicAdd(&colabs[gc], cp);                                   \
  }

  EPI_FN(0, nh0, nh1, nh2, nh3)
  EPI_FN(1, nh4, nh5, nh6, nh7)
#undef EPI_FN
#undef EPI_STORE
#undef STAGE
}

// ---------------------------------------------------------------------------
// thermal = 0.7*prev + 0.3*(colabs*CROSSTALK); tn[i] = CROSSTALK * sum thermal[j]/(i-j)^2
// ---------------------------------------------------------------------------
__global__ __launch_bounds__(256)
void thermal_tn(const float* __restrict__ colabs, const float* __restrict__ prev_thermal,
                float* __restrict__ thermal_out, float* __restrict__ tn_out, int has_prev)
{
  __shared__ float th[2048];
  __shared__ float inv[2048];
  const int t = threadIdx.x;
  for (int j = t; j < 2048; j += 256) {
    float lt = colabs[j] * CROSSTALK;
    float pv = has_prev ? prev_thermal[j] : 0.0f;
    th[j] = 0.7f * pv + 0.3f * lt;
    float d = (float)j;
    inv[j] = (j == 0) ? 0.0f : 1.0f / (d * d);
  }
  __syncthreads();
  const int i = blockIdx.x * 256 + t;
  float s = 0.0f;
  #pragma unroll 4
  for (int j = 0; j < 2048; ++j) {
    int d = i - j; d = d < 0 ? -d : d;
    s += th[j] * inv[d];
  }
  tn_out[i] = s * CROSSTALK;
  thermal_out[i] = th[i];
}

// ---------------------------------------------------------------------------
// Final: out[b,:] = F_COH * (x2[b,:] @ Wout^T) + foldout  (coherence + thermal
// folded into scale/bias; no RNG). a2 is fragment-native fp16 (128x64 blocks).
// ---------------------------------------------------------------------------
__global__ __launch_bounds__(256)
void final_out(const _Float16* __restrict__ a2n, const float* __restrict__ Wout,
               const float* __restrict__ foldout, float* __restrict__ out)
{
  const int wave = threadIdx.x >> 6;
  const int lane = threadIdx.x & 63;
  const int b = blockIdx.x * 4 + wave;
  float acc0 = 0.0f, acc1 = 0.0f;
  #pragma unroll
  for (int i = 0; i < 8; ++i) {
    int h = lane * 4 + i * 256;
    half4 v4 = *(const half4*)&a2n[cnat_idx(b, h)];
    float4 w0 = *(const float4*)&Wout[h];
    float4 w1 = *(const float4*)&Wout[2048 + h];
    float xs[4]  = {(float)v4[0], (float)v4[1], (float)v4[2], (float)v4[3]};
    float w0s[4] = {w0.x, w0.y, w0.z, w0.w};
    float w1s[4] = {w1.x, w1.y, w1.z, w1.w};
    #pragma unroll
    for (int e = 0; e < 4; ++e) {
      acc0 = fmaf(xs[e], w0s[e], acc0);
      acc1 = fmaf(xs[e], w1s[e], acc1);
    }
  }
  #pragma unroll
  for (int off = 32; off > 0; off >>= 1) {
    acc0 += __shfl_down(acc0, off);
    acc1 += __shfl_down(acc1, off);
  }
  if (lane == 0) {
    out[(size_t)b * 2 + 0] = fmaf(F_COH, acc0, foldout[0]);
    out[(size_t)b * 2 + 1] = fmaf(F_COH, acc1, foldout[1]);
  }
}

extern "C" void kernel_launch(void* const* d_in, const int* in_sizes, int n_in,
                              void* d_out, int out_size, void* d_ws, size_t ws_size,
                              hipStream_t stream)
{
  (void)in_sizes; (void)n_in; (void)out_size; (void)ws_size;
  const float* x    = (const float*)d_in[0];
  const float* W1   = (const float*)d_in[1];
  const float* b1   = (const float*)d_in[2];
  const float* W2   = (const float*)d_in[3];
  const float* b2   = (const float*)d_in[4];
  const float* Wout = (const float*)d_in[5];
  const float* bout = (const float*)d_in[6];
  float* out = (float*)d_out;

  const int M = 8192, H = 2048, Din = 1024;
  const size_t MB = (size_t)1024 * 1024;

  char* ws = (char*)d_ws;
  // [0,32MB): a2 fragment-native fp16 (G2 out)
  _Float16* a2n = (_Float16*)ws;
  // [32,64MB): a1 in G2-A packed layout (G1 writes directly; G2 reads as A)
  _Float16* a1pk = (_Float16*)(ws + 32 * MB);
  // [64,80MB): xpk (G1 A = tanh(x), packed)
  _Float16* xpk = (_Float16*)(ws + 64 * MB);
  // [80,84MB): W1 packed; [84,92MB): W2 packed
  _Float16* W1p = (_Float16*)(ws + 80 * MB);
  _Float16* W2p = (_Float16*)(ws + 84 * MB);
  // [96MB,...): small arrays
  float* small = (float*)(ws + 96 * MB);
  float* colabs1  = small + 0 * H;
  float* colabs2  = small + 1 * H;
  float* thermal1 = small + 2 * H;
  float* thermal2 = small + 3 * H;
  float* tn1      = small + 4 * H;
  float* tn2      = small + 5 * H;
  float* foldb    = small + 6 * H;
  float* foldout  = small + 7 * H;

  // fold_in keys: key(42) = (0,42); fold_in(key, d) = threefry(key, [0,d]).
  // Phase keys (d=1,3) no longer needed - coherence folded into F_COH.
  uint32_t kn0a, kn0b, kn1a, kn1b;
  threefry2x32(0u, 42u, 0u, 0u, kn0a, kn0b);   // noise, layer 0
  threefry2x32(0u, 42u, 0u, 2u, kn1a, kn1b);   // noise, layer 1

  hipMemsetAsync(colabs1, 0, 2 * H * sizeof(float), stream);

  // packs: A planes rbbits=7, W planes rbbits=6 (= BN); kshift = log2(K/32)
  pack_plane<<<1024, 256, 0, stream>>>(W1, W1p, H, Din, 5, 6, 0);
  pack_plane<<<2048, 256, 0, stream>>>(W2, W2p, H, H, 6, 6, 0);
  pack_plane<<<2048, 256, 0, stream>>>(x, xpk, M, Din, 5, 7, 1);

  const int nblk = (M / BM) * (H / BN);   // 64*32 = 2048
  gemm_f16<0><<<nblk, 256, 0, stream>>>(xpk, W1p, b1, a1pk, colabs1,
                                        M, H, Din, 1.0f, kn0a, kn0b);
  thermal_tn<<<H / 256, 256, 0, stream>>>(colabs1, nullptr, thermal1, tn1, 0);
  // foldb = b2 + F*(tn1 @ W2^T); G2 computes tanh(F*(a1@W2^T) + foldb) + noise
  bias_fold<<<H / 4, 256, 0, stream>>>(tn1, W2, b2, foldb, H, H, F_COH);
  gemm_f16<1><<<nblk, 256, 0, stream>>>(a1pk, W2p, foldb, a2n, colabs2,
                                        M, H, H, F_COH, kn1a, kn1b);
  thermal_tn<<<H / 256, 256, 0, stream>>>(colabs2, thermal1, thermal2, tn2, 1);
  // foldout = bout + F*(tn2 @ Wout^T)
  bias_fold<<<1, 256, 0, stream>>>(tn2, Wout, bout, foldout, H, 2, F_COH);
  final_out<<<M / 4, 256, 0, stream>>>(a2n, Wout, foldout, out);
}